// Round 2
// baseline (309.641 us; speedup 1.0000x reference)
//
#include <hip/hip_runtime.h>

constexpr int Bv  = 8;
constexpr int NQ  = 512;
constexpr int NKV = 512;
constexpr int Hh  = 16;
constexpr int Dd  = 256;

// C[m][n] = sum_k A[m][k] * W[n][k] + bias[n];  M=4096, N=256, K=256.
// 64x32 tile, 256 threads, 4x2 per thread. Double-buffered LDS, ONE barrier
// per k-tile, register prefetch overlaps global loads with FMA.
// Grid (64,8) = 512 blocks -> 2 blocks/CU, 8 waves/CU.
constexpr int BM = 64, BN = 32, BK = 16;

__global__ __launch_bounds__(256) void gemm_abt(
    const float* __restrict__ A, const float* __restrict__ W,
    const float* __restrict__ bias, float* __restrict__ C) {
  __shared__ float As[2][BK][BM + 4];
  __shared__ float Ws[2][BK][BN + 4];
  const int t  = threadIdx.x;
  const int m0 = blockIdx.x * BM;
  const int n0 = blockIdx.y * BN;
  const int ar = t >> 2;          // 0..63  A-row within tile
  const int ak = (t & 3) << 2;    // 0,4,8,12
  const int wr = (t & 127) >> 2;  // 0..31  W-row within tile
  const bool doW = (t < 128);
  const int tx = t & 15;          // n-pair
  const int ty = t >> 4;          // m-quad

  float acc[4][2] = {};

  // prefetch tile 0
  float4 av = *(const float4*)(A + (size_t)(m0 + ar) * 256 + ak);
  float4 wv = make_float4(0.f, 0.f, 0.f, 0.f);
  if (doW) wv = *(const float4*)(W + (size_t)(n0 + wr) * 256 + ak);

  // store tile 0
  As[0][ak + 0][ar] = av.x; As[0][ak + 1][ar] = av.y;
  As[0][ak + 2][ar] = av.z; As[0][ak + 3][ar] = av.w;
  if (doW) {
    Ws[0][ak + 0][wr] = wv.x; Ws[0][ak + 1][wr] = wv.y;
    Ws[0][ak + 2][wr] = wv.z; Ws[0][ak + 3][wr] = wv.w;
  }
  __syncthreads();

  for (int ti = 0; ti < 256 / BK; ++ti) {
    const int cur = ti & 1;
    const bool last = (ti == 256 / BK - 1);
    if (!last) {  // prefetch tile ti+1 (in flight during FMA below)
      const int kn = (ti + 1) * BK;
      av = *(const float4*)(A + (size_t)(m0 + ar) * 256 + kn + ak);
      if (doW) wv = *(const float4*)(W + (size_t)(n0 + wr) * 256 + kn + ak);
    }
#pragma unroll
    for (int k = 0; k < BK; ++k) {
      float a_[4], w_[2];
      *(float4*)a_ = *(const float4*)&As[cur][k][ty << 2];
      *(float2*)w_ = *(const float2*)&Ws[cur][k][tx << 1];
#pragma unroll
      for (int i = 0; i < 4; ++i)
#pragma unroll
        for (int j = 0; j < 2; ++j)
          acc[i][j] = fmaf(a_[i], w_[j], acc[i][j]);
    }
    if (!last) {  // write tile ti+1 into the other buffer
      const int nb = cur ^ 1;
      As[nb][ak + 0][ar] = av.x; As[nb][ak + 1][ar] = av.y;
      As[nb][ak + 2][ar] = av.z; As[nb][ak + 3][ar] = av.w;
      if (doW) {
        Ws[nb][ak + 0][wr] = wv.x; Ws[nb][ak + 1][wr] = wv.y;
        Ws[nb][ak + 2][wr] = wv.z; Ws[nb][ak + 3][wr] = wv.w;
      }
    }
    __syncthreads();
  }

  const float2 bv = *(const float2*)(bias + n0 + (tx << 1));
#pragma unroll
  for (int i = 0; i < 4; ++i) {
    float2 cv;
    cv.x = acc[i][0] + bv.x;
    cv.y = acc[i][1] + bv.y;
    *(float2*)(C + (size_t)(m0 + (ty << 2) + i) * 256 + n0 + (tx << 1)) = cv;
  }
}

// Fused masked softmax + per-head aggregation + L2-norm rescale.
// Grid 512 blocks x 512 threads: block = (b, 8 q-rows), thread = 1 q-row,
// lane-contiguous dcol = lane*4 (h = lane>>2) -> wave's ds_read_b128 covers
// 1024 CONTIGUOUS bytes (conflict-free). 2 blocks/CU * 8 waves = 16 waves/CU.
__global__ __launch_bounds__(512) void attn_kernel(
    const float* __restrict__ msg, const int* __restrict__ adj,
    const float* __restrict__ proj, float* __restrict__ attn_out) {
  __shared__ float Psh[32 * Dd];  // 32 KB: proj[b, k0:k0+32, :]

  const int t    = threadIdx.x;
  const int lane = t & 63;
  const int dcol = lane << 2;     // 0..252, contiguous within wave
  const int h    = dcol >> 4;     // lane>>2: 4 lanes share (q,h) -> broadcast
  const int q8   = t >> 6;        // 0..7
  const int b    = blockIdx.x >> 6;
  const int q    = (blockIdx.x & 63) * 8 + q8;

  const float* mp = msg + ((size_t)(b * NQ + q) * NKV) * Hh + h;
  const int*   ap = adj + (size_t)(b * NQ + q) * NKV;
  const float* pb = proj + (size_t)b * NKV * Dd;

  float o[4] = {};
  float s = 0.f, r = 0.f;

  for (int k0 = 0; k0 < NKV; k0 += 32) {
    __syncthreads();
    {  // stage proj[b, k0:k0+32, :] -> LDS (coalesced float4, 4 per thread)
      const float4* src = (const float4*)(pb + (size_t)k0 * Dd);
      float4* dst = (float4*)Psh;
#pragma unroll
      for (int i = 0; i < 4; ++i) dst[t + i * 512] = src[t + i * 512];
    }
    __syncthreads();

#pragma unroll 2
    for (int kk4 = 0; kk4 < 32; kk4 += 4) {
      int a4[4];
      *(int4*)a4 = *(const int4*)(ap + k0 + kk4);
      float m4[4];
#pragma unroll
      for (int j = 0; j < 4; ++j)
        m4[j] = mp[(size_t)(k0 + kk4 + j) * Hh];
#pragma unroll
      for (int j = 0; j < 4; ++j) {
        const float e = (a4[j] > 0) ? __expf(m4[j]) : 0.0f;
        s += e;
        r = fmaf(e, e, r);
        float p[4];
        *(float4*)p = *(const float4*)(Psh + (kk4 + j) * Dd + dcol);
#pragma unroll
        for (int d = 0; d < 4; ++d) o[d] = fmaf(e, p[d], o[d]);
      }
    }
  }

  const float w = sqrtf(r) / (s * s);
  float4 outv;
  outv.x = o[0] * w; outv.y = o[1] * w;
  outv.z = o[2] * w; outv.w = o[3] * w;
  *(float4*)(attn_out + (size_t)(b * NQ + q) * Dd + dcol) = outv;
}

extern "C" void kernel_launch(void* const* d_in, const int* in_sizes, int n_in,
                              void* d_out, int out_size, void* d_ws, size_t ws_size,
                              hipStream_t stream) {
  const float* v_inv    = (const float*)d_in[0];
  const float* messages = (const float*)d_in[1];
  const int*   adj      = (const int*)d_in[2];
  const float* W_in     = (const float*)d_in[3];
  const float* b_in     = (const float*)d_in[4];
  const float* W_out    = (const float*)d_in[5];
  const float* b_out    = (const float*)d_in[6];
  float* out = (float*)d_out;

  float* proj = (float*)d_ws;                       // 4 MB: [B, NKV, D]
  float* attn = proj + (size_t)Bv * NKV * Dd;       // 4 MB: [B, NQ, D]

  dim3 gemm_grid(4096 / BM, 256 / BN);
  gemm_abt<<<gemm_grid, 256, 0, stream>>>(v_inv, W_in, b_in, proj);
  attn_kernel<<<512, 512, 0, stream>>>(messages, adj, proj, attn);
  gemm_abt<<<gemm_grid, 256, 0, stream>>>(attn, W_out, b_out, out);
}